// Round 12
// baseline (3797.202 us; speedup 1.0000x reference)
//
#include <hip/hip_runtime.h>

#define NENT 40000
#define NRELH 200   /* (N_REL-1)/2 */
#define NLAYER 6
#define NEDGE 300000

// y layout: [node][d][b]  (idx = (n*64 + d)*4 + b): y[h][*][0..3] is a
// contiguous 1KB block one wave gathers with a single float4/lane instruction.

__device__ __forceinline__ float rdlane(float v, int l) {
  return __uint_as_float(__builtin_amdgcn_readlane(__float_as_uint(v), l));
}

// ---------------- graph preprocessing (CSR build) ----------------

__global__ void k_count(const int* __restrict__ tri, int* __restrict__ cnt,
                        int* __restrict__ degm) {
  int e = blockIdx.x * blockDim.x + threadIdx.x;
  if (e >= NEDGE) return;
  int r = tri[3*e+1], t = tri[3*e+2];
  atomicAdd(&cnt[t], 1);
  if (r >= 1 && r < NRELH) atomicAdd(&degm[t], 1);
}

__global__ void k_scan(const int* __restrict__ cnt, int* __restrict__ off) {
  __shared__ int part[1024];
  int tid = threadIdx.x;
  int base = tid * 40;             // 1024*40 = 40960 >= NENT
  int s = 0;
  for (int i = 0; i < 40; ++i) { int idx = base + i; if (idx < NENT) s += cnt[idx]; }
  part[tid] = s;
  __syncthreads();
  for (int dd = 1; dd < 1024; dd <<= 1) {
    int v = (tid >= dd) ? part[tid - dd] : 0;
    __syncthreads();
    part[tid] += v;
    __syncthreads();
  }
  int run = part[tid] - s;
  for (int i = 0; i < 40; ++i) {
    int idx = base + i;
    if (idx < NENT) { off[idx] = run; run += cnt[idx]; }
  }
  if (tid == 1023) off[NENT] = part[1023];
}

__global__ void k_fill(const int* __restrict__ tri, const int* __restrict__ off,
                       int* __restrict__ cur, unsigned* __restrict__ ehr) {
  int e = blockIdx.x * blockDim.x + threadIdx.x;
  if (e >= NEDGE) return;
  int h = tri[3*e], r = tri[3*e+1], t = tri[3*e+2];
  int pos = off[t] + atomicAdd(&cur[t], 1);
  ehr[pos] = (unsigned)h | ((unsigned)r << 16);   // h < 65536, r < 512
}

// ---------------- layer 0 init: y0 = x0 @ We0^T + be0 ----------------
// W in 64 pinned VGPRs, broadcast via v_readlane: ZERO LDS (R2-proven pattern).

__global__ __launch_bounds__(256, 4)
void k_init(const float* __restrict__ We, const float* __restrict__ be,
            float* __restrict__ y, const float* __restrict__ ent,
            const float* __restrict__ qe, const int* __restrict__ head,
            const int* __restrict__ rel, const int* __restrict__ degm) {
  int lane = threadIdx.x & 63, wv = threadIdx.x >> 6;
  float Wr[64];
  #pragma unroll
  for (int k4 = 0; k4 < 16; ++k4) {
    float4 w = *reinterpret_cast<const float4*>(We + lane*64 + k4*4);
    Wr[4*k4] = w.x; Wr[4*k4+1] = w.y; Wr[4*k4+2] = w.z; Wr[4*k4+3] = w.w;
  }
  #pragma unroll
  for (int k = 0; k < 64; ++k) asm volatile("" : "+v"(Wr[k]));  // pin: no remat
  float bv = be[lane];
  int h0=head[0], h1=head[1], h2=head[2], h3=head[3];
  int r0=rel[0],  r1=rel[1],  r2=rel[2],  r3=rel[3];
  int stride = gridDim.x*4;
  for (int n = blockIdx.x*4 + wv; n < NENT; n += stride) {
    float basev = (degm[n] >= 3) ? ent[(size_t)n*64 + lane] : -0.375f; // 1/8-0.5
    float4 xv;   // lane holds x[n][d=lane][0..3]
    xv.x = (h0==n) ? qe[r0*64+lane] : basev;
    xv.y = (h1==n) ? qe[r1*64+lane] : basev;
    xv.z = (h2==n) ? qe[r2*64+lane] : basev;
    xv.w = (h3==n) ? qe[r3*64+lane] : basev;
    float4 acc = make_float4(bv, bv, bv, bv);
    #pragma unroll
    for (int k = 0; k < 64; ++k) {
      float w = Wr[k];
      acc.x = fmaf(rdlane(xv.x, k), w, acc.x);
      acc.y = fmaf(rdlane(xv.y, k), w, acc.y);
      acc.z = fmaf(rdlane(xv.z, k), w, acc.z);
      acc.w = fmaf(rdlane(xv.w, k), w, acc.w);
    }
    *reinterpret_cast<float4*>(y + ((size_t)n*64 + lane)*4) = acc;
  }
}

// ---------------- fused layer kernel ----------------
// upd = segsum(relw[r] o y[h]);  z = upd @ Wl^T + bl + y[n];  xn = relu(LN(z));
// !LAST: y_next[n] = xn @ We_next^T + be_next      LAST: out[b][n] = xn . wcls + bc
//
// LDS-pipe diet (R10 post-mortem): matmul1 via Wl-in-VGPR + readlane (0 LDS);
// matmul2 via XOR-swizzled per-lane ds_read_b128 We (16 instrs) + [b][d] scratch.
// 512 thr, __launch_bounds__(512,3) -> VGPR cap 170 (body ~140, no spill).

template<bool LAST>
__global__ __launch_bounds__(512, 3)
void k_fused(const float* __restrict__ y, const unsigned* __restrict__ ehr,
             const int* __restrict__ off, const float* __restrict__ relw,
             const float* __restrict__ Wl, const float* __restrict__ bl,
             const float* __restrict__ lng, const float* __restrict__ lnb,
             const float* __restrict__ Wen, const float* __restrict__ ben,
             const float* __restrict__ wcls, const float* __restrict__ bcls,
             float* __restrict__ ynext, float* __restrict__ out) {
  __shared__ float sWe[4096];   // We_next, row-major XOR-swizzled (16 KB; unused when LAST)
  __shared__ float sc[2048];    // 8 waves x 256 floats scratch (8 KB)
  int tid = threadIdx.x, lane = tid & 63, wv = tid >> 6;
  if (!LAST) {
    for (int idx = tid; idx < 1024; idx += 512) {
      int e = idx >> 4, j = idx & 15;
      float4 v = *reinterpret_cast<const float4*>(Wen + e*64 + 4*j);
      *reinterpret_cast<float4*>(&sWe[e*64 + ((j ^ (e & 15)) * 4)]) = v;
    }
    __syncthreads();
  }
  // Wl row in 64 pinned VGPRs (lane = output dim e)
  float Wr[64];
  #pragma unroll
  for (int k4 = 0; k4 < 16; ++k4) {
    float4 w = *reinterpret_cast<const float4*>(Wl + lane*64 + k4*4);
    Wr[4*k4] = w.x; Wr[4*k4+1] = w.y; Wr[4*k4+2] = w.z; Wr[4*k4+3] = w.w;
  }
  #pragma unroll
  for (int k = 0; k < 64; ++k) asm volatile("" : "+v"(Wr[k]));  // pin: no remat
  float blv = bl[lane], g = lng[lane], bb = lnb[lane];
  float bev = LAST ? 0.f : ben[lane];
  float wc  = LAST ? wcls[lane] : 0.f;
  float bc  = LAST ? bcls[0] : 0.f;
  float* wsc = sc + wv*256;
  int stride = gridDim.x*8;
  for (int n = blockIdx.x*8 + wv; n < NENT; n += stride) {
    int c0 = __builtin_amdgcn_readfirstlane(off[n]);
    int c1 = __builtin_amdgcn_readfirstlane(off[n+1]);
    // residual load issued early, overlaps the gather
    float4 res = *reinterpret_cast<const float4*>(y + ((size_t)n*64 + lane)*4);
    float4 a0 = make_float4(0,0,0,0), a1 = make_float4(0,0,0,0);
    for (int j = c0; j < c1; j += 4) {
      int j1 = (j+1 < c1) ? j+1 : j;
      int j2 = (j+2 < c1) ? j+2 : j;
      int j3 = (j+3 < c1) ? j+3 : j;
      unsigned e0 = ehr[j], e1 = ehr[j1], e2 = ehr[j2], e3 = ehr[j3];
      float m1 = (j+1 < c1) ? 1.f : 0.f;
      float m2 = (j+2 < c1) ? 1.f : 0.f;
      float m3 = (j+3 < c1) ? 1.f : 0.f;
      int ha = (int)(e0 & 0xffffu), ra = (int)(e0 >> 16);
      int hb = (int)(e1 & 0xffffu), rb = (int)(e1 >> 16);
      int hc = (int)(e2 & 0xffffu), rc = (int)(e2 >> 16);
      int hd = (int)(e3 & 0xffffu), rd = (int)(e3 >> 16);
      float w0 = relw[ra*64 + lane];
      float w1 = relw[rb*64 + lane] * m1;
      float w2 = relw[rc*64 + lane] * m2;
      float w3 = relw[rd*64 + lane] * m3;
      float4 v0 = *reinterpret_cast<const float4*>(y + ((size_t)ha*64 + lane)*4);
      float4 v1 = *reinterpret_cast<const float4*>(y + ((size_t)hb*64 + lane)*4);
      float4 v2 = *reinterpret_cast<const float4*>(y + ((size_t)hc*64 + lane)*4);
      float4 v3 = *reinterpret_cast<const float4*>(y + ((size_t)hd*64 + lane)*4);
      a0.x = fmaf(w0, v0.x, a0.x); a0.y = fmaf(w0, v0.y, a0.y);
      a0.z = fmaf(w0, v0.z, a0.z); a0.w = fmaf(w0, v0.w, a0.w);
      a1.x = fmaf(w1, v1.x, a1.x); a1.y = fmaf(w1, v1.y, a1.y);
      a1.z = fmaf(w1, v1.z, a1.z); a1.w = fmaf(w1, v1.w, a1.w);
      a0.x = fmaf(w2, v2.x, a0.x); a0.y = fmaf(w2, v2.y, a0.y);
      a0.z = fmaf(w2, v2.z, a0.z); a0.w = fmaf(w2, v2.w, a0.w);
      a1.x = fmaf(w3, v3.x, a1.x); a1.y = fmaf(w3, v3.y, a1.y);
      a1.z = fmaf(w3, v3.z, a1.z); a1.w = fmaf(w3, v3.w, a1.w);
    }
    float4 acc = make_float4(a0.x+a1.x, a0.y+a1.y, a0.z+a1.z, a0.w+a1.w);
    // matmul1: z = upd @ Wl^T + bl + y[n]  -- readlane broadcast, ZERO LDS
    float4 z = make_float4(blv+res.x, blv+res.y, blv+res.z, blv+res.w);
    #pragma unroll
    for (int k = 0; k < 64; ++k) {
      float w = Wr[k];
      z.x = fmaf(rdlane(acc.x, k), w, z.x);
      z.y = fmaf(rdlane(acc.y, k), w, z.y);
      z.z = fmaf(rdlane(acc.z, k), w, z.z);
      z.w = fmaf(rdlane(acc.w, k), w, z.w);
    }
    // LayerNorm over the 64 lanes (feature dim), then ReLU
    float4 s = z;
    #pragma unroll
    for (int m = 32; m >= 1; m >>= 1) {
      s.x += __shfl_xor(s.x, m, 64); s.y += __shfl_xor(s.y, m, 64);
      s.z += __shfl_xor(s.z, m, 64); s.w += __shfl_xor(s.w, m, 64);
    }
    float4 dv = make_float4(z.x - s.x*0.015625f, z.y - s.y*0.015625f,
                            z.z - s.z*0.015625f, z.w - s.w*0.015625f);
    float4 q = make_float4(dv.x*dv.x, dv.y*dv.y, dv.z*dv.z, dv.w*dv.w);
    #pragma unroll
    for (int m = 32; m >= 1; m >>= 1) {
      q.x += __shfl_xor(q.x, m, 64); q.y += __shfl_xor(q.y, m, 64);
      q.z += __shfl_xor(q.z, m, 64); q.w += __shfl_xor(q.w, m, 64);
    }
    float4 xn;
    xn.x = fmaxf(dv.x * rsqrtf(q.x*0.015625f + 1e-5f) * g + bb, 0.f);
    xn.y = fmaxf(dv.y * rsqrtf(q.y*0.015625f + 1e-5f) * g + bb, 0.f);
    xn.z = fmaxf(dv.z * rsqrtf(q.z*0.015625f + 1e-5f) * g + bb, 0.f);
    xn.w = fmaxf(dv.w * rsqrtf(q.w*0.015625f + 1e-5f) * g + bb, 0.f);
    if (LAST) {
      float4 p = make_float4(xn.x*wc, xn.y*wc, xn.z*wc, xn.w*wc);
      #pragma unroll
      for (int m = 32; m >= 1; m >>= 1) {
        p.x += __shfl_xor(p.x, m, 64); p.y += __shfl_xor(p.y, m, 64);
        p.z += __shfl_xor(p.z, m, 64); p.w += __shfl_xor(p.w, m, 64);
      }
      float pv = (lane == 0) ? p.x : (lane == 1) ? p.y : (lane == 2) ? p.z : p.w;
      if (lane < 4) out[(size_t)lane*NENT + n] = pv + bc;
    } else {
      // matmul2: y_next = xn @ We_next^T + be_next  -- SCHEME-1 (R4-proven):
      // scratch [b][d] (4 b32 writes) + 16 per-lane swizzled b128 weight reads.
      wsc[  0+lane] = xn.x; wsc[ 64+lane] = xn.y;
      wsc[128+lane] = xn.z; wsc[192+lane] = xn.w;
      float4 yn = make_float4(bev, bev, bev, bev);
      #pragma unroll
      for (int k4 = 0; k4 < 16; ++k4) {
        float4 w4 = *reinterpret_cast<const float4*>(&sWe[lane*64 + ((k4 ^ (lane & 15)) * 4)]);
        float4 u0 = *reinterpret_cast<const float4*>(wsc +   0 + k4*4);  // uniform
        float4 u1 = *reinterpret_cast<const float4*>(wsc +  64 + k4*4);
        float4 u2 = *reinterpret_cast<const float4*>(wsc + 128 + k4*4);
        float4 u3 = *reinterpret_cast<const float4*>(wsc + 192 + k4*4);
        yn.x = fmaf(u0.x, w4.x, yn.x); yn.x = fmaf(u0.y, w4.y, yn.x);
        yn.x = fmaf(u0.z, w4.z, yn.x); yn.x = fmaf(u0.w, w4.w, yn.x);
        yn.y = fmaf(u1.x, w4.x, yn.y); yn.y = fmaf(u1.y, w4.y, yn.y);
        yn.y = fmaf(u1.z, w4.z, yn.y); yn.y = fmaf(u1.w, w4.w, yn.y);
        yn.z = fmaf(u2.x, w4.x, yn.z); yn.z = fmaf(u2.y, w4.y, yn.z);
        yn.z = fmaf(u2.z, w4.z, yn.z); yn.z = fmaf(u2.w, w4.w, yn.z);
        yn.w = fmaf(u3.x, w4.x, yn.w); yn.w = fmaf(u3.y, w4.y, yn.w);
        yn.w = fmaf(u3.z, w4.z, yn.w); yn.w = fmaf(u3.w, w4.w, yn.w);
      }
      *reinterpret_cast<float4*>(ynext + ((size_t)n*64 + lane)*4) = yn;
    }
  }
}

// ---------------- launch ----------------

extern "C" void kernel_launch(void* const* d_in, const int* in_sizes, int n_in,
                              void* d_out, int out_size, void* d_ws, size_t ws_size,
                              hipStream_t stream) {
  const int*   head = (const int*)  d_in[0];
  const int*   rel  = (const int*)  d_in[1];
  const int*   tri  = (const int*)  d_in[2];
  const float* ent  = (const float*)d_in[3];
  const float* qe   = (const float*)d_in[4];
  const float* rw   = (const float*)d_in[5];
  const float* We   = (const float*)d_in[6];
  const float* be   = (const float*)d_in[7];
  const float* Wl   = (const float*)d_in[8];
  const float* bl   = (const float*)d_in[9];
  const float* lg   = (const float*)d_in[10];
  const float* lb   = (const float*)d_in[11];
  const float* wc   = (const float*)d_in[12];
  const float* bc   = (const float*)d_in[13];

  char* ws = (char*)d_ws;
  size_t o = 0;
  auto alloc = [&](size_t bytes) { void* p = ws + o; o += (bytes + 255) & ~255ull; return p; };
  float*    ya   = (float*)   alloc((size_t)NENT*256*sizeof(float)); // 41 MB, [n][d][b]
  float*    yb   = (float*)   alloc((size_t)NENT*256*sizeof(float)); // 41 MB, [n][d][b]
  int*      cnt  = (int*)     alloc(NENT*sizeof(int));   // cnt, degm, cur contiguous
  int*      degm = (int*)     alloc(NENT*sizeof(int));   // (NENT*4 % 256 == 0)
  int*      cur  = (int*)     alloc(NENT*sizeof(int));
  int*      off  = (int*)     alloc((NENT+1)*sizeof(int));
  unsigned* ehr  = (unsigned*)alloc(NEDGE*sizeof(unsigned));
  (void)ws_size; (void)in_sizes; (void)n_in; (void)out_size;

  hipMemsetAsync(cnt, 0, (size_t)3*NENT*sizeof(int), stream);  // cnt, degm, cur

  k_count<<<(NEDGE+255)/256, 256, 0, stream>>>(tri, cnt, degm);
  k_scan <<<1, 1024, 0, stream>>>(cnt, off);
  k_fill <<<(NEDGE+255)/256, 256, 0, stream>>>(tri, off, cur, ehr);

  k_init<<<2048, 256, 0, stream>>>(We, be, ya, ent, qe, head, rel, degm);

  const int GRID = 1536;  // grid-stride; residency is VGPR-capped (~12 waves/CU)
  for (int i = 0; i < NLAYER; ++i) {
    const float* src = (i % 2 == 0) ? ya : yb;
    float*       dst = (i % 2 == 0) ? yb : ya;
    const float* Wli = Wl + (size_t)i*4096;
    const float* bli = bl + (size_t)i*64;
    const float* rwi = rw + (size_t)i*401*64;
    const float* lgi = lg + (size_t)i*64;
    const float* lbi = lb + (size_t)i*64;
    const float* Wen = We + (size_t)(i+1)*4096;  // next layer's entity matmul
    const float* ben = be + (size_t)(i+1)*64;
    if (i == NLAYER-1)
      k_fused<true ><<<GRID, 512, 0, stream>>>(src, ehr, off, rwi, Wli, bli, lgi, lbi,
                                               We, be, wc, bc, dst, (float*)d_out);
    else
      k_fused<false><<<GRID, 512, 0, stream>>>(src, ehr, off, rwi, Wli, bli, lgi, lbi,
                                               Wen, ben, wc, bc, dst, (float*)d_out);
  }
}

// Round 13
// 713.520 us; speedup vs baseline: 5.3218x; 5.3218x over previous
//
#include <hip/hip_runtime.h>

#define NENT 40000
#define NRELH 200   /* (N_REL-1)/2 */
#define NLAYER 6
#define NEDGE 300000

// y layout: [node][d][b]  (idx = (n*64 + d)*4 + b): y[h][*][0..3] is a
// contiguous 1KB block one wave gathers with a single float4/lane instruction.

__device__ __forceinline__ float rdlane(float v, int l) {
  return __uint_as_float(__builtin_amdgcn_readlane(__float_as_uint(v), l));
}

// ---------------- graph preprocessing (CSR build) ----------------

__global__ void k_count(const int* __restrict__ tri, int* __restrict__ cnt,
                        int* __restrict__ degm) {
  int e = blockIdx.x * blockDim.x + threadIdx.x;
  if (e >= NEDGE) return;
  int r = tri[3*e+1], t = tri[3*e+2];
  atomicAdd(&cnt[t], 1);
  if (r >= 1 && r < NRELH) atomicAdd(&degm[t], 1);
}

__global__ void k_scan(const int* __restrict__ cnt, int* __restrict__ off) {
  __shared__ int part[1024];
  int tid = threadIdx.x;
  int base = tid * 40;             // 1024*40 = 40960 >= NENT
  int s = 0;
  for (int i = 0; i < 40; ++i) { int idx = base + i; if (idx < NENT) s += cnt[idx]; }
  part[tid] = s;
  __syncthreads();
  for (int dd = 1; dd < 1024; dd <<= 1) {
    int v = (tid >= dd) ? part[tid - dd] : 0;
    __syncthreads();
    part[tid] += v;
    __syncthreads();
  }
  int run = part[tid] - s;
  for (int i = 0; i < 40; ++i) {
    int idx = base + i;
    if (idx < NENT) { off[idx] = run; run += cnt[idx]; }
  }
  if (tid == 1023) off[NENT] = part[1023];
}

__global__ void k_fill(const int* __restrict__ tri, const int* __restrict__ off,
                       int* __restrict__ cur, unsigned* __restrict__ ehr) {
  int e = blockIdx.x * blockDim.x + threadIdx.x;
  if (e >= NEDGE) return;
  int h = tri[3*e], r = tri[3*e+1], t = tri[3*e+2];
  int pos = off[t] + atomicAdd(&cur[t], 1);
  ehr[pos] = (unsigned)h | ((unsigned)r << 16);   // h < 65536, r < 512
}

// ---------------- layer 0 init: y0 = x0 @ We0^T + be0 ----------------
// R10-proven form (SCHEME0 LDS matmul), unchanged.

__global__ __launch_bounds__(384, 6)
void k_init(const float* __restrict__ We, const float* __restrict__ be,
            float* __restrict__ y, const float* __restrict__ ent,
            const float* __restrict__ qe, const int* __restrict__ head,
            const int* __restrict__ rel, const int* __restrict__ degm) {
  __shared__ float sWT[4096];   // WT[k][e] = We[e][k]  (16 KB)
  __shared__ float sc[1536];    // 6 waves x 256 floats scratch (6 KB)
  int tid = threadIdx.x, lane = tid & 63, wv = tid >> 6;
  for (int idx = tid; idx < 1024; idx += 384) {
    int e = idx >> 4, k4 = (idx & 15) * 4;
    float4 w = *reinterpret_cast<const float4*>(We + e*64 + k4);
    sWT[(k4+0)*64+e] = w.x; sWT[(k4+1)*64+e] = w.y;
    sWT[(k4+2)*64+e] = w.z; sWT[(k4+3)*64+e] = w.w;
  }
  __syncthreads();
  float bv = be[lane];
  int h0=head[0], h1=head[1], h2=head[2], h3=head[3];
  int r0=rel[0],  r1=rel[1],  r2=rel[2],  r3=rel[3];
  float* wsc = sc + wv*256;
  int stride = gridDim.x*6;
  for (int n = blockIdx.x*6 + wv; n < NENT; n += stride) {
    float basev = (degm[n] >= 3) ? ent[(size_t)n*64 + lane] : -0.375f; // 1/8-0.5
    float4 xv;
    xv.x = (h0==n) ? qe[r0*64+lane] : basev;
    xv.y = (h1==n) ? qe[r1*64+lane] : basev;
    xv.z = (h2==n) ? qe[r2*64+lane] : basev;
    xv.w = (h3==n) ? qe[r3*64+lane] : basev;
    *reinterpret_cast<float4*>(wsc + lane*4) = xv;      // lane holds x[d=lane][0..3]
    float4 acc = make_float4(bv, bv, bv, bv);
    #pragma unroll 8
    for (int k = 0; k < 64; ++k) {
      float4 u = *reinterpret_cast<const float4*>(wsc + k*4);  // uniform broadcast
      float  w = sWT[k*64 + lane];                             // lane = output e
      acc.x = fmaf(u.x, w, acc.x); acc.y = fmaf(u.y, w, acc.y);
      acc.z = fmaf(u.z, w, acc.z); acc.w = fmaf(u.w, w, acc.w);
    }
    *reinterpret_cast<float4*>(y + ((size_t)n*64 + lane)*4) = acc;
  }
}

// ---------------- fused layer kernel ----------------
// upd = segsum(relw[r] o y[h]);  z = upd @ Wl^T + bl + y[n];  xn = relu(LN(z));
// !LAST: y_next[n] = xn @ We_next^T + be_next      LAST: out[b][n] = xn . wcls + bc
//
// LDS diet v2 (R12 lesson: NO pinned weights): broadcast operand via rdlane
// (it's already in registers), weights via 16 XOR-swizzled per-lane
// ds_read_b128 per matmul. No scratch, no uniform LDS reads.
// LDS-pipe ops/node: ~261 -> ~80. Register live set unchanged (~60, cap 85).

template<bool LAST>
__global__ __launch_bounds__(384, 6)
void k_fused(const float* __restrict__ y, const unsigned* __restrict__ ehr,
             const int* __restrict__ off, const float* __restrict__ relw,
             const float* __restrict__ Wl, const float* __restrict__ bl,
             const float* __restrict__ lng, const float* __restrict__ lnb,
             const float* __restrict__ Wen, const float* __restrict__ ben,
             const float* __restrict__ wcls, const float* __restrict__ bcls,
             float* __restrict__ ynext, float* __restrict__ out) {
  __shared__ float sWl[4096];   // Wl row-major XOR-swizzled (16 KB)
  __shared__ float sWe[4096];   // We_next row-major XOR-swizzled (16 KB; unused when LAST)
  int tid = threadIdx.x, lane = tid & 63;
  for (int idx = tid; idx < 1024; idx += 384) {
    int e = idx >> 4, j = idx & 15;
    float4 w = *reinterpret_cast<const float4*>(Wl + e*64 + 4*j);
    *reinterpret_cast<float4*>(&sWl[e*64 + ((j ^ (e & 15)) * 4)]) = w;
    if (!LAST) {
      float4 v = *reinterpret_cast<const float4*>(Wen + e*64 + 4*j);
      *reinterpret_cast<float4*>(&sWe[e*64 + ((j ^ (e & 15)) * 4)]) = v;
    }
  }
  __syncthreads();
  int wv = tid >> 6;
  float blv = bl[lane], g = lng[lane], bb = lnb[lane];
  float bev = LAST ? 0.f : ben[lane];
  float wc  = LAST ? wcls[lane] : 0.f;
  float bc  = LAST ? bcls[0] : 0.f;
  int stride = gridDim.x*6;
  for (int n = blockIdx.x*6 + wv; n < NENT; n += stride) {
    // prevent hoisting the loop-invariant LDS weight reads into registers
    asm volatile("" ::: "memory");
    int c0 = __builtin_amdgcn_readfirstlane(off[n]);
    int c1 = __builtin_amdgcn_readfirstlane(off[n+1]);
    // residual load issued early, overlaps the gather
    float4 res = *reinterpret_cast<const float4*>(y + ((size_t)n*64 + lane)*4);
    float4 a0 = make_float4(0,0,0,0), a1 = make_float4(0,0,0,0);
    for (int j = c0; j < c1; j += 4) {
      int j1 = (j+1 < c1) ? j+1 : j;
      int j2 = (j+2 < c1) ? j+2 : j;
      int j3 = (j+3 < c1) ? j+3 : j;
      unsigned e0 = ehr[j], e1 = ehr[j1], e2 = ehr[j2], e3 = ehr[j3];
      float m1 = (j+1 < c1) ? 1.f : 0.f;
      float m2 = (j+2 < c1) ? 1.f : 0.f;
      float m3 = (j+3 < c1) ? 1.f : 0.f;
      int ha = (int)(e0 & 0xffffu), ra = (int)(e0 >> 16);
      int hb = (int)(e1 & 0xffffu), rb = (int)(e1 >> 16);
      int hc = (int)(e2 & 0xffffu), rc = (int)(e2 >> 16);
      int hd = (int)(e3 & 0xffffu), rd = (int)(e3 >> 16);
      float w0 = relw[ra*64 + lane];
      float w1 = relw[rb*64 + lane] * m1;
      float w2 = relw[rc*64 + lane] * m2;
      float w3 = relw[rd*64 + lane] * m3;
      float4 v0 = *reinterpret_cast<const float4*>(y + ((size_t)ha*64 + lane)*4);
      float4 v1 = *reinterpret_cast<const float4*>(y + ((size_t)hb*64 + lane)*4);
      float4 v2 = *reinterpret_cast<const float4*>(y + ((size_t)hc*64 + lane)*4);
      float4 v3 = *reinterpret_cast<const float4*>(y + ((size_t)hd*64 + lane)*4);
      a0.x = fmaf(w0, v0.x, a0.x); a0.y = fmaf(w0, v0.y, a0.y);
      a0.z = fmaf(w0, v0.z, a0.z); a0.w = fmaf(w0, v0.w, a0.w);
      a1.x = fmaf(w1, v1.x, a1.x); a1.y = fmaf(w1, v1.y, a1.y);
      a1.z = fmaf(w1, v1.z, a1.z); a1.w = fmaf(w1, v1.w, a1.w);
      a0.x = fmaf(w2, v2.x, a0.x); a0.y = fmaf(w2, v2.y, a0.y);
      a0.z = fmaf(w2, v2.z, a0.z); a0.w = fmaf(w2, v2.w, a0.w);
      a1.x = fmaf(w3, v3.x, a1.x); a1.y = fmaf(w3, v3.y, a1.y);
      a1.z = fmaf(w3, v3.z, a1.z); a1.w = fmaf(w3, v3.w, a1.w);
    }
    float4 acc = make_float4(a0.x+a1.x, a0.y+a1.y, a0.z+a1.z, a0.w+a1.w);
    // matmul1: z[lane] = sum_k upd[k]*Wl[lane][k] + bl + res
    // upd[k] broadcast via rdlane (VALU); weights 16 swizzled b128 LDS reads.
    float4 z = make_float4(blv+res.x, blv+res.y, blv+res.z, blv+res.w);
    #pragma unroll
    for (int k4 = 0; k4 < 16; ++k4) {
      float4 w4 = *reinterpret_cast<const float4*>(&sWl[lane*64 + ((k4 ^ (lane & 15)) * 4)]);
      z.x = fmaf(rdlane(acc.x, 4*k4+0), w4.x, z.x);
      z.y = fmaf(rdlane(acc.y, 4*k4+0), w4.x, z.y);
      z.z = fmaf(rdlane(acc.z, 4*k4+0), w4.x, z.z);
      z.w = fmaf(rdlane(acc.w, 4*k4+0), w4.x, z.w);
      z.x = fmaf(rdlane(acc.x, 4*k4+1), w4.y, z.x);
      z.y = fmaf(rdlane(acc.y, 4*k4+1), w4.y, z.y);
      z.z = fmaf(rdlane(acc.z, 4*k4+1), w4.y, z.z);
      z.w = fmaf(rdlane(acc.w, 4*k4+1), w4.y, z.w);
      z.x = fmaf(rdlane(acc.x, 4*k4+2), w4.z, z.x);
      z.y = fmaf(rdlane(acc.y, 4*k4+2), w4.z, z.y);
      z.z = fmaf(rdlane(acc.z, 4*k4+2), w4.z, z.z);
      z.w = fmaf(rdlane(acc.w, 4*k4+2), w4.z, z.w);
      z.x = fmaf(rdlane(acc.x, 4*k4+3), w4.w, z.x);
      z.y = fmaf(rdlane(acc.y, 4*k4+3), w4.w, z.y);
      z.z = fmaf(rdlane(acc.z, 4*k4+3), w4.w, z.z);
      z.w = fmaf(rdlane(acc.w, 4*k4+3), w4.w, z.w);
    }
    // LayerNorm over the 64 lanes (feature dim), then ReLU
    float4 s = z;
    #pragma unroll
    for (int m = 32; m >= 1; m >>= 1) {
      s.x += __shfl_xor(s.x, m, 64); s.y += __shfl_xor(s.y, m, 64);
      s.z += __shfl_xor(s.z, m, 64); s.w += __shfl_xor(s.w, m, 64);
    }
    float4 dv = make_float4(z.x - s.x*0.015625f, z.y - s.y*0.015625f,
                            z.z - s.z*0.015625f, z.w - s.w*0.015625f);
    float4 q = make_float4(dv.x*dv.x, dv.y*dv.y, dv.z*dv.z, dv.w*dv.w);
    #pragma unroll
    for (int m = 32; m >= 1; m >>= 1) {
      q.x += __shfl_xor(q.x, m, 64); q.y += __shfl_xor(q.y, m, 64);
      q.z += __shfl_xor(q.z, m, 64); q.w += __shfl_xor(q.w, m, 64);
    }
    float4 xn;
    xn.x = fmaxf(dv.x * rsqrtf(q.x*0.015625f + 1e-5f) * g + bb, 0.f);
    xn.y = fmaxf(dv.y * rsqrtf(q.y*0.015625f + 1e-5f) * g + bb, 0.f);
    xn.z = fmaxf(dv.z * rsqrtf(q.z*0.015625f + 1e-5f) * g + bb, 0.f);
    xn.w = fmaxf(dv.w * rsqrtf(q.w*0.015625f + 1e-5f) * g + bb, 0.f);
    if (LAST) {
      float4 p = make_float4(xn.x*wc, xn.y*wc, xn.z*wc, xn.w*wc);
      #pragma unroll
      for (int m = 32; m >= 1; m >>= 1) {
        p.x += __shfl_xor(p.x, m, 64); p.y += __shfl_xor(p.y, m, 64);
        p.z += __shfl_xor(p.z, m, 64); p.w += __shfl_xor(p.w, m, 64);
      }
      float pv = (lane == 0) ? p.x : (lane == 1) ? p.y : (lane == 2) ? p.z : p.w;
      if (lane < 4) out[(size_t)lane*NENT + n] = pv + bc;
    } else {
      // matmul2: yn[lane] = sum_e xn[e]*We[lane][e] + be  (same rdlane form)
      float4 yn = make_float4(bev, bev, bev, bev);
      #pragma unroll
      for (int k4 = 0; k4 < 16; ++k4) {
        float4 w4 = *reinterpret_cast<const float4*>(&sWe[lane*64 + ((k4 ^ (lane & 15)) * 4)]);
        yn.x = fmaf(rdlane(xn.x, 4*k4+0), w4.x, yn.x);
        yn.y = fmaf(rdlane(xn.y, 4*k4+0), w4.x, yn.y);
        yn.z = fmaf(rdlane(xn.z, 4*k4+0), w4.x, yn.z);
        yn.w = fmaf(rdlane(xn.w, 4*k4+0), w4.x, yn.w);
        yn.x = fmaf(rdlane(xn.x, 4*k4+1), w4.y, yn.x);
        yn.y = fmaf(rdlane(xn.y, 4*k4+1), w4.y, yn.y);
        yn.z = fmaf(rdlane(xn.z, 4*k4+1), w4.y, yn.z);
        yn.w = fmaf(rdlane(xn.w, 4*k4+1), w4.y, yn.w);
        yn.x = fmaf(rdlane(xn.x, 4*k4+2), w4.z, yn.x);
        yn.y = fmaf(rdlane(xn.y, 4*k4+2), w4.z, yn.y);
        yn.z = fmaf(rdlane(xn.z, 4*k4+2), w4.z, yn.z);
        yn.w = fmaf(rdlane(xn.w, 4*k4+2), w4.z, yn.w);
        yn.x = fmaf(rdlane(xn.x, 4*k4+3), w4.w, yn.x);
        yn.y = fmaf(rdlane(xn.y, 4*k4+3), w4.w, yn.y);
        yn.z = fmaf(rdlane(xn.z, 4*k4+3), w4.w, yn.z);
        yn.w = fmaf(rdlane(xn.w, 4*k4+3), w4.w, yn.w);
      }
      *reinterpret_cast<float4*>(ynext + ((size_t)n*64 + lane)*4) = yn;
    }
  }
}

// ---------------- launch ----------------

extern "C" void kernel_launch(void* const* d_in, const int* in_sizes, int n_in,
                              void* d_out, int out_size, void* d_ws, size_t ws_size,
                              hipStream_t stream) {
  const int*   head = (const int*)  d_in[0];
  const int*   rel  = (const int*)  d_in[1];
  const int*   tri  = (const int*)  d_in[2];
  const float* ent  = (const float*)d_in[3];
  const float* qe   = (const float*)d_in[4];
  const float* rw   = (const float*)d_in[5];
  const float* We   = (const float*)d_in[6];
  const float* be   = (const float*)d_in[7];
  const float* Wl   = (const float*)d_in[8];
  const float* bl   = (const float*)d_in[9];
  const float* lg   = (const float*)d_in[10];
  const float* lb   = (const float*)d_in[11];
  const float* wc   = (const float*)d_in[12];
  const float* bc   = (const float*)d_in[13];

  char* ws = (char*)d_ws;
  size_t o = 0;
  auto alloc = [&](size_t bytes) { void* p = ws + o; o += (bytes + 255) & ~255ull; return p; };
  float*    ya   = (float*)   alloc((size_t)NENT*256*sizeof(float)); // 41 MB, [n][d][b]
  float*    yb   = (float*)   alloc((size_t)NENT*256*sizeof(float)); // 41 MB, [n][d][b]
  int*      cnt  = (int*)     alloc(NENT*sizeof(int));   // cnt, degm, cur contiguous
  int*      degm = (int*)     alloc(NENT*sizeof(int));   // (NENT*4 % 256 == 0)
  int*      cur  = (int*)     alloc(NENT*sizeof(int));
  int*      off  = (int*)     alloc((NENT+1)*sizeof(int));
  unsigned* ehr  = (unsigned*)alloc(NEDGE*sizeof(unsigned));
  (void)ws_size; (void)in_sizes; (void)n_in; (void)out_size;

  hipMemsetAsync(cnt, 0, (size_t)3*NENT*sizeof(int), stream);  // cnt, degm, cur

  k_count<<<(NEDGE+255)/256, 256, 0, stream>>>(tri, cnt, degm);
  k_scan <<<1, 1024, 0, stream>>>(cnt, off);
  k_fill <<<(NEDGE+255)/256, 256, 0, stream>>>(tri, off, cur, ehr);

  const int GRID = 1024;  // grid-stride, 6 waves/block
  k_init<<<GRID, 384, 0, stream>>>(We, be, ya, ent, qe, head, rel, degm);

  for (int i = 0; i < NLAYER; ++i) {
    const float* src = (i % 2 == 0) ? ya : yb;
    float*       dst = (i % 2 == 0) ? yb : ya;
    const float* Wli = Wl + (size_t)i*4096;
    const float* bli = bl + (size_t)i*64;
    const float* rwi = rw + (size_t)i*401*64;
    const float* lgi = lg + (size_t)i*64;
    const float* lbi = lb + (size_t)i*64;
    const float* Wen = We + (size_t)(i+1)*4096;  // next layer's entity matmul
    const float* ben = be + (size_t)(i+1)*64;
    if (i == NLAYER-1)
      k_fused<true ><<<GRID, 384, 0, stream>>>(src, ehr, off, rwi, Wli, bli, lgi, lbi,
                                               We, be, wc, bc, dst, (float*)d_out);
    else
      k_fused<false><<<GRID, 384, 0, stream>>>(src, ehr, off, rwi, Wli, bli, lgi, lbi,
                                               Wen, ben, wc, bc, dst, (float*)d_out);
  }
}